// Round 5
// baseline (1011.333 us; speedup 1.0000x reference)
//
#include <hip/hip_runtime.h>
#include <cstdint>
#include <cstddef>

// ---------------- problem constants ----------------
#define TSTEPS 192
#define BATCH  4096
#define FRAW   20
#define FCONV  22
#define FCNN   11
#define HID    40
#define NOUT   21
#define ROWSPB 8            // rows per block (MFMA cols 8..15 zero-padded)
#define NTH    320          // 5 waves x (2 gate-tiles of 16 gates each)
#define NBLK   (BATCH/ROWSPB)   // 512 blocks -> 2 blocks/CU

#define FEAT_OFF 4096       // ws: [0,1536) stats ; feat at byte offset 4096

typedef _Float16 half8 __attribute__((ext_vector_type(8)));
typedef float    f32x4 __attribute__((ext_vector_type(4)));
#define MFMA16(a,b,c) __builtin_amdgcn_mfma_f32_16x16x32_f16(a,b,c,0,0,0)

__device__ __forceinline__ float sigm_(float x){ return 1.f/(1.f+__expf(-x)); }
__device__ __forceinline__ float tanh_(float x){ float e=__expf(2.f*x); return 1.f-2.f/(e+1.f); }
__device__ __forceinline__ float softplus_(float x){ return fmaxf(x,0.f)+log1pf(__expf(-fabsf(x))); }

// fragment-layout offset (in halves) of logical k, row mr within one buffer:
// [chunk=k>>5][q=(k>>3)&3][mr][i=k&7], chunk stride 512, q stride 128
__device__ __forceinline__ int offk(int k, int mr){
    return ((k>>5)*4 + ((k>>3)&3))*128 + mr*8 + (k&7);
}

// -------- kernel 1: per-t BN affine params (unchanged) ----------------------
__global__ __launch_bounds__(256)
void stats_kernel(const float* __restrict__ x_enc, const float* __restrict__ y_enc,
                  const float* __restrict__ conv_w, const float* __restrict__ conv_b,
                  const float* __restrict__ bn_w, const float* __restrict__ bn_b,
                  float* __restrict__ stats)
{
    const int t = blockIdx.x;
    const float w0=conv_w[0], w1=conv_w[1], w2=conv_w[2], cb=conv_b[0];
    const float* src = (t < 96) ? (x_enc + (size_t)t*21) : (y_enc + (size_t)(t-96)*21);
    float s=0.f, ss=0.f;
    for (int b = threadIdx.x; b < BATCH; b += 256) {
        const float* xr = src + (size_t)b*2016;
        float xv[FRAW];
        #pragma unroll
        for (int f=0; f<FRAW; ++f) xv[f] = xr[f];
        #pragma unroll
        for (int i=0; i<FCONV; ++i) {
            float y = fmaf(w0, xv[(i+18)%20], fmaf(w1, xv[(i+19)%20], fmaf(w2, xv[i%20], cb)));
            s += y; ss = fmaf(y, y, ss);
        }
    }
    __shared__ float rs[256], rq[256];
    rs[threadIdx.x]=s; rq[threadIdx.x]=ss;
    __syncthreads();
    for (int o=128; o>0; o>>=1){
        if (threadIdx.x < o){ rs[threadIdx.x]+=rs[threadIdx.x+o]; rq[threadIdx.x]+=rq[threadIdx.x+o]; }
        __syncthreads();
    }
    if (threadIdx.x == 0){
        const float N = (float)(BATCH*FCONV);
        float mu  = rs[0]/N;
        float var = rq[0]/N - mu*mu;
        float A   = rsqrtf(var + 1e-5f) * bn_w[0];
        stats[2*t]   = A;
        stats[2*t+1] = bn_b[0] - mu*A;
    }
}

// -------- kernel 2: conv + BN + ELU + maxpool (unchanged) -------------------
__global__ __launch_bounds__(256)
void feat_kernel(const float* __restrict__ x_enc, const float* __restrict__ y_enc,
                 const float* __restrict__ conv_w, const float* __restrict__ conv_b,
                 const float* __restrict__ stats, float* __restrict__ feat)
{
    const int t = blockIdx.x;
    const int b = blockIdx.y*256 + threadIdx.x;
    const float w0=conv_w[0], w1=conv_w[1], w2=conv_w[2], cb=conv_b[0];
    const float A = stats[2*t], Bc = stats[2*t+1];
    const float* xr = ((t<96) ? (x_enc + (size_t)t*21) : (y_enc + (size_t)(t-96)*21)) + (size_t)b*2016;
    float xv[FRAW];
    #pragma unroll
    for (int f=0; f<FRAW; ++f) xv[f] = xr[f];
    float yv[FCONV];
    #pragma unroll
    for (int i=0; i<FCONV; ++i) {
        float y = fmaf(w0, xv[(i+18)%20], fmaf(w1, xv[(i+19)%20], fmaf(w2, xv[i%20], cb)));
        y = fmaf(y, A, Bc);
        yv[i] = (y > 0.f) ? y : expm1f(y);
    }
    float* fo = feat + ((size_t)t*BATCH + b)*FCNN;
    #pragma unroll
    for (int i=0; i<FCNN; ++i) {
        float m = (i==0) ? fmaxf(yv[0], yv[1])
                         : fmaxf(yv[2*i-1], fmaxf(yv[2*i], yv[2*i+1]));
        fo[i] = m;
    }
}

// -------- kernel 3: persistent MFMA LSTM, 1 barrier/step --------------------
// 512 blocks x 320 thr (5 waves x 2 tiles), 2 blocks/CU, 8 rows/block.
// Mod-3 state buffers: phase1(t) writes buf (t+1)%3 (B0) + buf t%3 (B1 k<40);
// phase2(t) reads buf t%3, writes h1 -> buf (t+1)%3 (B1 k 40..79);
// heads(t-1) runs in iter t after the barrier, reads B1 bufs (t-1)%3 & t%3.
// All concurrent read/write buffer indices are distinct mod 3 (audited).
// LDS fragment layout [buf][chunk][q][mr][8]: lane l reads base + l*16B.
__global__ __launch_bounds__(NTH, 3)
void lstm_kernel(const float* __restrict__ feat,
                 const float* __restrict__ w_ih0, const float* __restrict__ w_hh0, const float* __restrict__ b0,
                 const float* __restrict__ w_ih1, const float* __restrict__ w_hh1, const float* __restrict__ b1,
                 const float* __restrict__ w_gamma, const float* __restrict__ b_gamma,
                 const float* __restrict__ w_eta,   const float* __restrict__ b_eta,
                 float* __restrict__ out)
{
    __shared__ __align__(16) _Float16 B0h_[3][2][4][16][8];   // K=64: feat|h0|pad
    __shared__ __align__(16) _Float16 B0l_[3][2][4][16][8];
    __shared__ __align__(16) _Float16 B1h_[3][3][4][16][8];   // K=96: h0|h1|pad
    __shared__ __align__(16) _Float16 B1l_[3][3][4][16][8];
    _Float16* B0h = &B0h_[0][0][0][0][0];
    _Float16* B0l = &B0l_[0][0][0][0][0];
    _Float16* B1h = &B1h_[0][0][0][0][0];
    _Float16* B1l = &B1l_[0][0][0][0][0];

    const int tid  = threadIdx.x;
    const int l    = tid & 63;
    const int wv   = tid >> 6;        // wave 0..4 owns tiles 2wv, 2wv+1
    const int q    = l >> 4;
    const int mr   = l & 15;          // batch row (valid < 8)
    const int row0 = blockIdx.x * ROWSPB;

    // ---- zero LDS ----
    { uint32_t* z;
      z=(uint32_t*)B0h; for(int i=tid;i<1536;i+=NTH) z[i]=0u;
      z=(uint32_t*)B0l; for(int i=tid;i<1536;i+=NTH) z[i]=0u;
      z=(uint32_t*)B1h; for(int i=tid;i<2304;i+=NTH) z[i]=0u;
      z=(uint32_t*)B1l; for(int i=tid;i<2304;i+=NTH) z[i]=0u; }

    // ---- A fragments (hi/lo split). Tile g covers units 8wv+4g .. +3.
    // lane holds A[row=mr][k=q*8+i]; gate rows unit-major: RA=(gate)*40+unit.
    half8 a0h[2][2], a0l[2][2], a1h[2][3], a1l[2][3], ahd[3];
    #pragma unroll
    for (int g=0; g<2; ++g){
        const int uA = 8*wv + 4*g + (mr >> 2);
        const int RA = (mr & 3)*40 + uA;
        #pragma unroll
        for (int f=0; f<2; ++f){
            #pragma unroll
            for (int i=0; i<8; ++i){
                int k = f*32 + q*8 + i;
                float v = (k<11) ? w_ih0[RA*11 + k] : ((k<51) ? w_hh0[RA*40 + k - 11] : 0.f);
                _Float16 h = (_Float16)v;
                a0h[g][f][i] = h; a0l[g][f][i] = (_Float16)(v - (float)h);
            }
        }
        #pragma unroll
        for (int f=0; f<3; ++f){
            #pragma unroll
            for (int i=0; i<8; ++i){
                int k = f*32 + q*8 + i;
                float v = (k<40) ? w_ih1[RA*40 + k] : ((k<80) ? w_hh1[RA*40 + k - 40] : 0.f);
                _Float16 h = (_Float16)v;
                a1h[g][f][i] = h; a1l[g][f][i] = (_Float16)(v - (float)h);
            }
        }
    }
    {   // heads A (fp16-single: heads are non-recurrent, error ~1e-4)
        int jo = 16*wv + mr;
        #pragma unroll
        for (int f=0; f<3; ++f){
            #pragma unroll
            for (int i=0; i<8; ++i){
                int k = f*32 + q*8 + i;
                float v = 0.f;
                if (wv < 2 && jo < NOUT && k < 80){
                    int col = (k<40) ? 2*k : 2*(k-40)+1;   // hp interleave folded
                    v = (jo==0) ? w_gamma[col] : w_eta[(jo-1)*80 + col];
                }
                ahd[f][i] = (_Float16)v;
            }
        }
    }

    // ---- biases: lane owns units uG0=8wv+q (tile 2wv) and uG1=uG0+4
    const int uG0 = 8*wv + q, uG1 = uG0 + 4;
    f32x4 bias0[2], bias1[2], biash;
    bias0[0][0]=b0[uG0]; bias0[0][1]=b0[40+uG0]; bias0[0][2]=b0[80+uG0]; bias0[0][3]=b0[120+uG0];
    bias0[1][0]=b0[uG1]; bias0[1][1]=b0[40+uG1]; bias0[1][2]=b0[80+uG1]; bias0[1][3]=b0[120+uG1];
    bias1[0][0]=b1[uG0]; bias1[0][1]=b1[40+uG0]; bias1[0][2]=b1[80+uG0]; bias1[0][3]=b1[120+uG0];
    bias1[1][0]=b1[uG1]; bias1[1][1]=b1[40+uG1]; bias1[1][2]=b1[80+uG1]; bias1[1][3]=b1[120+uG1];
    #pragma unroll
    for (int e=0; e<4; ++e){
        int jo = 16*wv + 4*q + e;
        biash[e] = (wv < 2 && jo < NOUT) ? ((jo==0) ? b_gamma[0] : b_eta[jo-1]) : 0.f;
    }

    // ---- per-thread write offsets (halves, within one buffer) ----
    const int woB0_0 = offk(11+uG0, mr), woB0_1 = offk(11+uG1, mr);
    const int woB1_0 = offk(uG0, mr),    woB1_1 = offk(uG1, mr);
    const int woH1_0 = offk(40+uG0, mr), woH1_1 = offk(40+uG1, mr);

    // ---- feat staging threads: tid 192..279 (88 = 8 rows x 11) ----
    const int  ft     = tid - 192;
    const bool isFeat = (ft >= 0 && ft < ROWSPB*FCNN);
    const int  frr    = isFeat ? (ft / FCNN) : 0;
    const int  fff    = isFeat ? (ft - FCNN*frr) : 0;
    const int  woF    = offk(fff, frr);
    const float* fbase = feat + (size_t)(row0 + frr)*FCNN + fff;

    __syncthreads();   // zero-init visible
    if (isFeat){
        float v = fbase[0];     // t = 0
        _Float16 h = (_Float16)v;
        B0h[woF] = h; B0l[woF] = (_Float16)(v - (float)h);
    }
    __syncthreads();

    float c0[2] = {0.f, 0.f}, c1[2] = {0.f, 0.f};
    int m = 0, mp = 0;

    for (int t=0; t<TSTEPS; ++t){
        const int mn = (m==2) ? 0 : m+1;
        float fpre = 0.f;
        if (isFeat && t+1 < TSTEPS)
            fpre = fbase[(size_t)(t+1)*BATCH*FCNN];

        // ---- phase 1: layer0, K=64, 2 tiles interleaved (12 MFMA, 2 chains)
        {
            const _Float16* p0h = B0h + m*1024 + l*8;
            const _Float16* p0l = B0l + m*1024 + l*8;
            half8 xh0 = *(const half8*)(p0h);
            half8 xh1 = *(const half8*)(p0h + 512);
            half8 xl0 = *(const half8*)(p0l);
            half8 xl1 = *(const half8*)(p0l + 512);
            f32x4 A0 = bias0[0], A1 = bias0[1];
            A0 = MFMA16(a0h[0][0], xh0, A0);  A1 = MFMA16(a0h[1][0], xh0, A1);
            A0 = MFMA16(a0l[0][0], xh0, A0);  A1 = MFMA16(a0l[1][0], xh0, A1);
            A0 = MFMA16(a0h[0][0], xl0, A0);  A1 = MFMA16(a0h[1][0], xl0, A1);
            A0 = MFMA16(a0h[0][1], xh1, A0);  A1 = MFMA16(a0h[1][1], xh1, A1);
            A0 = MFMA16(a0l[0][1], xh1, A0);  A1 = MFMA16(a0l[1][1], xh1, A1);
            A0 = MFMA16(a0h[0][1], xl1, A0);  A1 = MFMA16(a0h[1][1], xl1, A1);
            #pragma unroll
            for (int g=0; g<2; ++g){
                f32x4 acc = g ? A1 : A0;
                float ig=sigm_(acc[0]), fg=sigm_(acc[1]), gv=tanh_(acc[2]), og=sigm_(acc[3]);
                c0[g] = fmaf(fg, c0[g], ig*gv);
                float h0v = og * tanh_(c0[g]);
                _Float16 hh = (_Float16)h0v, hl = (_Float16)(h0v - (float)hh);
                if (mr < ROWSPB){
                    int ob0 = mn*1024 + (g ? woB0_1 : woB0_0);
                    int ob1 = m*1536  + (g ? woB1_1 : woB1_0);
                    B0h[ob0] = hh; B0l[ob0] = hl;   // next step's L0 input
                    B1h[ob1] = hh; B1l[ob1] = hl;   // this step's L1 input
                }
            }
        }
        if (isFeat && t+1 < TSTEPS){
            _Float16 h = (_Float16)fpre;
            B0h[mn*1024 + woF] = h; B0l[mn*1024 + woF] = (_Float16)(fpre - (float)h);
        }
        __syncthreads();   // the ONLY barrier per step

        // ---- phase 2: layer1, K=96 (h0(t) | h1(t-1) | pad), 18 MFMA
        {
            const _Float16* p1h = B1h + m*1536 + l*8;
            const _Float16* p1l = B1l + m*1536 + l*8;
            f32x4 C0 = bias1[0], C1 = bias1[1];
            #pragma unroll
            for (int f=0; f<3; ++f){
                half8 yh = *(const half8*)(p1h + f*512);
                half8 yl = *(const half8*)(p1l + f*512);
                C0 = MFMA16(a1h[0][f], yh, C0);  C1 = MFMA16(a1h[1][f], yh, C1);
                C0 = MFMA16(a1l[0][f], yh, C0);  C1 = MFMA16(a1l[1][f], yh, C1);
                C0 = MFMA16(a1h[0][f], yl, C0);  C1 = MFMA16(a1h[1][f], yl, C1);
            }
            #pragma unroll
            for (int g=0; g<2; ++g){
                f32x4 acc = g ? C1 : C0;
                float ig=sigm_(acc[0]), fg=sigm_(acc[1]), gv=tanh_(acc[2]), og=sigm_(acc[3]);
                c1[g] = fmaf(fg, c1[g], ig*gv);
                float h1v = og * tanh_(c1[g]);
                _Float16 hh = (_Float16)h1v, hl = (_Float16)(h1v - (float)hh);
                if (mr < ROWSPB){
                    int ob = mn*1536 + (g ? woH1_1 : woH1_0);
                    B1h[ob] = hh; B1l[ob] = hl;    // h1(t) for step t+1 / heads(t)
                }
            }
        }

        // ---- heads(t-1): reads B1 bufs mp (h0(t-1), chunk0 + chunk1/q0) and
        // m (h1(t-1), chunk1/q>=1 + chunk2). Concurrent writers touch buf mn only.
        if (wv < 2 && t > 0){
            const _Float16* ba = B1h + mp*1536 + l*8;
            const _Float16* bb = B1h + m*1536  + l*8;
            half8 z0 = *(const half8*)(ba);
            half8 z1 = *(const half8*)(((q==0) ? ba : bb) + 512);
            half8 z2 = *(const half8*)(bb + 1024);
            f32x4 H = biash;
            H = MFMA16(ahd[0], z0, H);
            H = MFMA16(ahd[1], z1, H);
            H = MFMA16(ahd[2], z2, H);
            if (mr < ROWSPB){
                float* op = out + ((size_t)(t-1)*BATCH + row0 + mr)*NOUT;
                #pragma unroll
                for (int e=0; e<4; ++e){
                    int jo = 16*wv + 4*q + e;
                    if (jo < NOUT) op[jo] = softplus_(H[e]);
                }
            }
        }
        mp = m; m = mn;
    }

    // ---- epilogue: heads(191). h0(191) in buf mp(=191%3), h1(191) in buf m.
    __syncthreads();
    if (wv < 2){
        const _Float16* ba = B1h + mp*1536 + l*8;
        const _Float16* bb = B1h + m*1536  + l*8;
        half8 z0 = *(const half8*)(ba);
        half8 z1 = *(const half8*)(((q==0) ? ba : bb) + 512);
        half8 z2 = *(const half8*)(bb + 1024);
        f32x4 H = biash;
        H = MFMA16(ahd[0], z0, H);
        H = MFMA16(ahd[1], z1, H);
        H = MFMA16(ahd[2], z2, H);
        if (mr < ROWSPB){
            float* op = out + ((size_t)(TSTEPS-1)*BATCH + row0 + mr)*NOUT;
            #pragma unroll
            for (int e=0; e<4; ++e){
                int jo = 16*wv + 4*q + e;
                if (jo < NOUT) op[jo] = softplus_(H[e]);
            }
        }
    }
}

// ---------------------------------------------------------------------------
extern "C" void kernel_launch(void* const* d_in, const int* in_sizes, int n_in,
                              void* d_out, int out_size, void* d_ws, size_t ws_size,
                              hipStream_t stream)
{
    (void)in_sizes; (void)n_in; (void)out_size; (void)ws_size;
    const float* x_enc   = (const float*)d_in[0];
    const float* y_enc   = (const float*)d_in[3];
    const float* conv_w  = (const float*)d_in[5];
    const float* conv_b  = (const float*)d_in[6];
    const float* bn_w    = (const float*)d_in[7];
    const float* bn_b    = (const float*)d_in[8];
    const float* w_ih0   = (const float*)d_in[9];
    const float* w_hh0   = (const float*)d_in[10];
    const float* b0      = (const float*)d_in[11];
    const float* w_ih1   = (const float*)d_in[12];
    const float* w_hh1   = (const float*)d_in[13];
    const float* b1      = (const float*)d_in[14];
    const float* w_gamma = (const float*)d_in[15];
    const float* b_gamma = (const float*)d_in[16];
    const float* w_eta   = (const float*)d_in[17];
    const float* b_eta   = (const float*)d_in[18];

    float* out   = (float*)d_out;
    float* stats = (float*)d_ws;
    float* feat  = (float*)((char*)d_ws + FEAT_OFF);

    stats_kernel<<<TSTEPS, 256, 0, stream>>>(x_enc, y_enc, conv_w, conv_b, bn_w, bn_b, stats);
    feat_kernel<<<dim3(TSTEPS, BATCH/256), 256, 0, stream>>>(x_enc, y_enc, conv_w, conv_b, stats, feat);
    lstm_kernel<<<NBLK, NTH, 0, stream>>>(feat,
        w_ih0, w_hh0, b0, w_ih1, w_hh1, b1, w_gamma, b_gamma, w_eta, b_eta, out);
}